// Round 1
// baseline (84.195 us; speedup 1.0000x reference)
//
#include <hip/hip_runtime.h>
#include <math.h>

// Problem constants: B=32, Q=256, M=128, P=64, C=20 (+1 no-object)
constexpr int kB = 32;
constexpr int kQ = 256;
constexpr int kM = 128;
constexpr int kP = 64;
constexpr int kC = 20;
constexpr int kC1 = kC + 1;

constexpr int kPairsPerBlock = 16;                        // 16 (b,m) pairs per 256-thread block
constexpr int kBlocks = (kB * kM) / kPairsPerBlock;       // 256 blocks == 1 per CU

// ws layout (floats): poly partials [0,1024), dir partials [1024,2048),
//                     ce partials [2048,2304), completion counter @ [2304]
constexpr int kWsPoly = 0;
constexpr int kWsDir  = 1024;
constexpr int kWsCe   = 2048;
constexpr int kWsCnt  = 2304;

// ---------------------------------------------------------------------------
// Single fused kernel, 256 blocks (1/CU):
//  - each block stages 16 pairs (src+tgt polylines) into LDS via float4,
//    each of 4 waves computes 4 pairs of chamfer+direction partials;
//  - lanes 0-31 of wave 0 additionally compute cross-entropy for 32 queries
//    of this block's batch (8 blocks/batch cover all 256 queries);
//  - partials stored to ws with agent-scope atomic stores; last block to
//    finish (device-scope counter, zeroed by a 4-byte memset node) reduces
//    all 2304 partials and writes out[0..2]. No second kernel launch.
// ---------------------------------------------------------------------------
__global__ __launch_bounds__(256) void fused_kernel(const float* __restrict__ logits,
                                                    const float2* __restrict__ pred_poly,
                                                    const float2* __restrict__ tgt_poly,
                                                    const int* __restrict__ src_idx,
                                                    const int* __restrict__ labels,
                                                    float* __restrict__ ws,
                                                    float* __restrict__ out) {
    const int tid  = threadIdx.x;
    const int lane = tid & 63;
    const int w    = tid >> 6;
    const int bid  = blockIdx.x;

    __shared__ float2 s_src[kPairsPerBlock][kP];
    __shared__ float2 s_tgt[kPairsPerBlock][kP];
    __shared__ int    s_sidx[kPairsPerBlock];
    __shared__ int    c_idx[kM];
    __shared__ int    c_lab[kM];
    __shared__ int    s_last;
    __shared__ float  sp[4], sd[4], sc[4];

    const int base = bid * kPairsPerBlock;  // global pair base
    const int b    = base >> 7;             // kM = 128; block never spans batches

    if (tid < kPairsPerBlock) s_sidx[tid] = src_idx[base + tid];
    if (tid < kM) {
        c_idx[tid] = src_idx[b * kM + tid];
        c_lab[tid] = labels[b * kM + tid];
    }
    __syncthreads();

    // ---- stage 16 pairs x (32 src + 32 tgt) float4 = 1024 float4 with 256 threads
    #pragma unroll
    for (int i = 0; i < 4; ++i) {
        const int g      = i * 256 + tid;
        const int p      = g >> 6;
        const int within = g & 63;
        if (within < 32) {
            const float4* s4 = reinterpret_cast<const float4*>(
                pred_poly + (size_t)(b * kQ + s_sidx[p]) * kP);
            reinterpret_cast<float4*>(s_src[p])[within] = s4[within];
        } else {
            const float4* t4 = reinterpret_cast<const float4*>(
                tgt_poly + (size_t)(base + p) * kP);
            reinterpret_cast<float4*>(s_tgt[p])[within - 32] = t4[within - 32];
        }
    }
    __syncthreads();

    // ---- polyline chamfer + direction: wave w handles pairs 4w..4w+3 ----
    float accPoly = 0.f, accDir = 0.f;
    #pragma unroll
    for (int i = 0; i < 4; ++i) {
        const int p = w * 4 + i;
        const float2 ms = s_src[p][lane];
        const float2 mt = s_tgt[p][lane];
        const float4* srow = reinterpret_cast<const float4*>(s_src[p]);
        const float4* trow = reinterpret_cast<const float4*>(s_tgt[p]);
        float minJ = 1e30f, minI = 1e30f;
        #pragma unroll 8
        for (int jj = 0; jj < kP / 2; ++jj) {        // 2 points per b128 read
            const float4 tj = trow[jj];              // broadcast — conflict-free
            const float4 sj = srow[jj];
            minJ = fminf(minJ, fminf(fabsf(ms.x - tj.x) + fabsf(ms.y - tj.y),
                                     fabsf(ms.x - tj.z) + fabsf(ms.y - tj.w)));
            minI = fminf(minI, fminf(fabsf(sj.x - mt.x) + fabsf(sj.y - mt.y),
                                     fabsf(sj.z - mt.x) + fabsf(sj.w - mt.y)));
        }
        float val = minI + minJ;
        #pragma unroll
        for (int off = 32; off > 0; off >>= 1) val += __shfl_down(val, off, 64);
        if (lane == 0) {
            accPoly += val;
            const float2 s0 = s_src[p][0], s1 = s_src[p][kP - 1];
            const float2 t0 = s_tgt[p][0], t1 = s_tgt[p][kP - 1];
            const float sdx = s1.x - s0.x, sdy = s1.y - s0.y;
            const float tdx = t1.x - t0.x, tdy = t1.y - t0.y;
            const float sn = sqrtf(sdx * sdx + sdy * sdy) + 1e-6f;
            const float tn = sqrtf(tdx * tdx + tdy * tdy) + 1e-6f;
            accDir += 1.0f - (sdx * tdx + sdy * tdy) / (sn * tn);
        }
    }
    if (lane == 0) {
        const int wid = bid * 4 + w;  // 0..1023
        __hip_atomic_store(&ws[kWsPoly + wid], accPoly, __ATOMIC_RELAXED, __HIP_MEMORY_SCOPE_AGENT);
        __hip_atomic_store(&ws[kWsDir + wid],  accDir,  __ATOMIC_RELAXED, __HIP_MEMORY_SCOPE_AGENT);
    }

    // ---- cross entropy: lanes 0-31 of wave 0, 32 queries of batch b ----
    if (w == 0) {
        float ceVal = 0.f;
        if (lane < 32) {
            const int q = ((bid & 7) << 5) + lane;
            // numpy scatter: last occurrence wins -> ascending overwrite
            int tc = kC;
            #pragma unroll 4
            for (int m = 0; m < kM; ++m) {
                if (c_idx[m] == q) tc = c_lab[m];
            }
            const float* lp = logits + (size_t)(b * kQ + q) * kC1;
            float mx = -1e30f;
            #pragma unroll
            for (int c = 0; c < kC1; ++c) mx = fmaxf(mx, lp[c]);
            float se = 0.f, vt = 0.f;
            #pragma unroll
            for (int c = 0; c < kC1; ++c) {           // static index + cndmask select:
                const float x = lp[c];                 // no runtime-indexed array -> no scratch
                se += __expf(x - mx);
                if (c == tc) vt = x;
            }
            ceVal = -(vt - mx - __logf(se));
        }
        #pragma unroll
        for (int off = 32; off > 0; off >>= 1) ceVal += __shfl_down(ceVal, off, 64);
        if (lane == 0)
            __hip_atomic_store(&ws[kWsCe + bid], ceVal, __ATOMIC_RELAXED, __HIP_MEMORY_SCOPE_AGENT);
    }

    // ---- last-block election. __syncthreads drains vmcnt, so all this block's
    //      agent-scope stores are visible before the release fetch_add. ----
    __syncthreads();
    if (tid == 0) {
        unsigned int* cnt = reinterpret_cast<unsigned int*>(ws + kWsCnt);
        const unsigned int old =
            __hip_atomic_fetch_add(cnt, 1u, __ATOMIC_ACQ_REL, __HIP_MEMORY_SCOPE_AGENT);
        s_last = (old == (unsigned int)(kBlocks - 1));
    }
    __syncthreads();
    if (!s_last) return;

    // ---- finalize (last block only): reduce 1024+1024+256 partials ----
    float p = 0.f, d = 0.f, c = 0.f;
    #pragma unroll
    for (int k = 0; k < 4; ++k) {
        p += __hip_atomic_load(&ws[kWsPoly + tid + 256 * k], __ATOMIC_RELAXED, __HIP_MEMORY_SCOPE_AGENT);
        d += __hip_atomic_load(&ws[kWsDir  + tid + 256 * k], __ATOMIC_RELAXED, __HIP_MEMORY_SCOPE_AGENT);
    }
    c = __hip_atomic_load(&ws[kWsCe + tid], __ATOMIC_RELAXED, __HIP_MEMORY_SCOPE_AGENT);

    #pragma unroll
    for (int off = 32; off > 0; off >>= 1) {
        p += __shfl_down(p, off, 64);
        d += __shfl_down(d, off, 64);
        c += __shfl_down(c, off, 64);
    }

    if (lane == 0) { sp[w] = p; sd[w] = d; sc[w] = c; }
    __syncthreads();
    if (tid == 0) {
        const float P = sp[0] + sp[1] + sp[2] + sp[3];
        const float D = sd[0] + sd[1] + sd[2] + sd[3];
        const float C = sc[0] + sc[1] + sc[2] + sc[3];
        out[0] = C * (1.0f / (float)(kB * kQ));
        out[1] = P * (0.5f / ((float)kP * (float)(kB * kM)));
        out[2] = D * (1.0f / (float)(kB * kM));
    }
}

extern "C" void kernel_launch(void* const* d_in, const int* in_sizes, int n_in,
                              void* d_out, int out_size, void* d_ws, size_t ws_size,
                              hipStream_t stream) {
    const float*  pred_logits = (const float*)d_in[0];
    const float2* pred_poly   = (const float2*)d_in[1];
    const float2* tgt_poly    = (const float2*)d_in[2];
    const int*    src_idx     = (const int*)d_in[3];
    const int*    labels      = (const int*)d_in[4];
    float* out = (float*)d_out;
    float* ws  = (float*)d_ws;

    // Counter cell must be 0 each iteration (ws is poisoned by the harness).
    // 4-byte memset is a graph-capture-legal node, far cheaper than a kernel.
    hipMemsetAsync(ws + kWsCnt, 0, sizeof(unsigned int), stream);

    fused_kernel<<<kBlocks, 256, 0, stream>>>(
        pred_logits, pred_poly, tgt_poly, src_idx, labels, ws, out);
}

// Round 2
// 78.185 us; speedup vs baseline: 1.0769x; 1.0769x over previous
//
#include <hip/hip_runtime.h>
#include <math.h>

// Problem constants: B=32, Q=256, M=128, P=64, C=20 (+1 no-object)
constexpr int kB = 32;
constexpr int kQ = 256;
constexpr int kM = 128;
constexpr int kP = 64;
constexpr int kC = 20;
constexpr int kC1 = kC + 1;

constexpr int kPairsPerBlock = 16;                   // 16 (b,m) pairs per 256-thread block
constexpr int kBlocks = (kB * kM) / kPairsPerBlock;  // 256 blocks == 1 per CU

// ws layout (floats): poly [0,256), dir [256,512), ce [512,768) — one of each per block
constexpr int kWsPoly = 0;
constexpr int kWsDir  = 256;
constexpr int kWsCe   = 512;

// ---------------------------------------------------------------------------
// Stage 1: 256 blocks (1/CU), no atomics, 3 plain float stores per block.
//  - each block stages 16 pairs (src+tgt polylines) into LDS via float4;
//    each of 4 waves computes 4 pairs of chamfer+direction partials;
//  - lanes 0-31 of wave 0 additionally compute cross-entropy for 32 queries
//    of this block's batch (8 blocks/batch cover all 256 queries);
//  - wave partials are combined in LDS so the block emits exactly 3 floats.
// ---------------------------------------------------------------------------
__global__ __launch_bounds__(256) void partial_kernel(const float* __restrict__ logits,
                                                      const float2* __restrict__ pred_poly,
                                                      const float2* __restrict__ tgt_poly,
                                                      const int* __restrict__ src_idx,
                                                      const int* __restrict__ labels,
                                                      float* __restrict__ ws) {
    const int tid  = threadIdx.x;
    const int lane = tid & 63;
    const int w    = tid >> 6;
    const int bid  = blockIdx.x;

    __shared__ float2 s_src[kPairsPerBlock][kP];
    __shared__ float2 s_tgt[kPairsPerBlock][kP];
    __shared__ int    s_sidx[kPairsPerBlock];
    __shared__ int    c_idx[kM];
    __shared__ int    c_lab[kM];
    __shared__ float  sp[4], sd[4];

    const int base = bid * kPairsPerBlock;  // global pair base
    const int b    = base >> 7;             // kM = 128; block never spans batches

    if (tid < kPairsPerBlock) s_sidx[tid] = src_idx[base + tid];
    if (tid < kM) {
        c_idx[tid] = src_idx[b * kM + tid];
        c_lab[tid] = labels[b * kM + tid];
    }
    __syncthreads();

    // ---- stage 16 pairs x (32 src + 32 tgt) float4 = 1024 float4 with 256 threads
    #pragma unroll
    for (int i = 0; i < 4; ++i) {
        const int g      = i * 256 + tid;
        const int p      = g >> 6;
        const int within = g & 63;
        if (within < 32) {
            const float4* s4 = reinterpret_cast<const float4*>(
                pred_poly + (size_t)(b * kQ + s_sidx[p]) * kP);
            reinterpret_cast<float4*>(s_src[p])[within] = s4[within];
        } else {
            const float4* t4 = reinterpret_cast<const float4*>(
                tgt_poly + (size_t)(base + p) * kP);
            reinterpret_cast<float4*>(s_tgt[p])[within - 32] = t4[within - 32];
        }
    }
    __syncthreads();

    // ---- polyline chamfer + direction: wave w handles pairs 4w..4w+3 ----
    float accPoly = 0.f, accDir = 0.f;
    #pragma unroll
    for (int i = 0; i < 4; ++i) {
        const int p = w * 4 + i;
        const float2 ms = s_src[p][lane];
        const float2 mt = s_tgt[p][lane];
        const float4* srow = reinterpret_cast<const float4*>(s_src[p]);
        const float4* trow = reinterpret_cast<const float4*>(s_tgt[p]);
        float minJ = 1e30f, minI = 1e30f;
        #pragma unroll 8
        for (int jj = 0; jj < kP / 2; ++jj) {        // 2 points per b128 read
            const float4 tj = trow[jj];              // broadcast — conflict-free
            const float4 sj = srow[jj];
            minJ = fminf(minJ, fminf(fabsf(ms.x - tj.x) + fabsf(ms.y - tj.y),
                                     fabsf(ms.x - tj.z) + fabsf(ms.y - tj.w)));
            minI = fminf(minI, fminf(fabsf(sj.x - mt.x) + fabsf(sj.y - mt.y),
                                     fabsf(sj.z - mt.x) + fabsf(sj.w - mt.y)));
        }
        float val = minI + minJ;
        #pragma unroll
        for (int off = 32; off > 0; off >>= 1) val += __shfl_down(val, off, 64);
        if (lane == 0) {
            accPoly += val;
            const float2 s0 = s_src[p][0], s1 = s_src[p][kP - 1];
            const float2 t0 = s_tgt[p][0], t1 = s_tgt[p][kP - 1];
            const float sdx = s1.x - s0.x, sdy = s1.y - s0.y;
            const float tdx = t1.x - t0.x, tdy = t1.y - t0.y;
            const float sn = sqrtf(sdx * sdx + sdy * sdy) + 1e-6f;
            const float tn = sqrtf(tdx * tdx + tdy * tdy) + 1e-6f;
            accDir += 1.0f - (sdx * tdx + sdy * tdy) / (sn * tn);
        }
    }

    // ---- cross entropy: lanes 0-31 of wave 0, 32 queries of batch b ----
    if (w == 0) {
        float ceVal = 0.f;
        if (lane < 32) {
            const int q = ((bid & 7) << 5) + lane;
            // numpy scatter: last occurrence wins -> ascending overwrite
            int tc = kC;
            #pragma unroll 4
            for (int m = 0; m < kM; ++m) {
                if (c_idx[m] == q) tc = c_lab[m];
            }
            const float* lp = logits + (size_t)(b * kQ + q) * kC1;
            float mx = -1e30f;
            #pragma unroll
            for (int c = 0; c < kC1; ++c) mx = fmaxf(mx, lp[c]);
            float se = 0.f, vt = 0.f;
            #pragma unroll
            for (int c = 0; c < kC1; ++c) {           // static index + cndmask select:
                const float x = lp[c];                 // no runtime-indexed array -> no scratch
                se += __expf(x - mx);
                if (c == tc) vt = x;
            }
            ceVal = -(vt - mx - __logf(se));
        }
        #pragma unroll
        for (int off = 32; off > 0; off >>= 1) ceVal += __shfl_down(ceVal, off, 64);
        if (lane == 0) ws[kWsCe + bid] = ceVal;
    }

    // ---- block-level combine: 3 floats out per block ----
    if (lane == 0) { sp[w] = accPoly; sd[w] = accDir; }
    __syncthreads();
    if (tid == 0) {
        ws[kWsPoly + bid] = sp[0] + sp[1] + sp[2] + sp[3];
        ws[kWsDir + bid]  = sd[0] + sd[1] + sd[2] + sd[3];
    }
}

// ---------------------------------------------------------------------------
// Stage 2: single block reduces 256+256+256 partials, writes out[0..2].
// ---------------------------------------------------------------------------
__global__ __launch_bounds__(256) void finalize_kernel(const float* __restrict__ ws,
                                                       float* __restrict__ out) {
    const int tid  = threadIdx.x;
    const int lane = tid & 63;
    const int w    = tid >> 6;

    float p = ws[kWsPoly + tid];
    float d = ws[kWsDir + tid];
    float c = ws[kWsCe + tid];

    #pragma unroll
    for (int off = 32; off > 0; off >>= 1) {
        p += __shfl_down(p, off, 64);
        d += __shfl_down(d, off, 64);
        c += __shfl_down(c, off, 64);
    }

    __shared__ float sp[4], sd[4], sc[4];
    if (lane == 0) { sp[w] = p; sd[w] = d; sc[w] = c; }
    __syncthreads();
    if (tid == 0) {
        const float P = sp[0] + sp[1] + sp[2] + sp[3];
        const float D = sd[0] + sd[1] + sd[2] + sd[3];
        const float C = sc[0] + sc[1] + sc[2] + sc[3];
        out[0] = C * (1.0f / (float)(kB * kQ));
        out[1] = P * (0.5f / ((float)kP * (float)(kB * kM)));
        out[2] = D * (1.0f / (float)(kB * kM));
    }
}

extern "C" void kernel_launch(void* const* d_in, const int* in_sizes, int n_in,
                              void* d_out, int out_size, void* d_ws, size_t ws_size,
                              hipStream_t stream) {
    const float*  pred_logits = (const float*)d_in[0];
    const float2* pred_poly   = (const float2*)d_in[1];
    const float2* tgt_poly    = (const float2*)d_in[2];
    const int*    src_idx     = (const int*)d_in[3];
    const int*    labels      = (const int*)d_in[4];
    float* out = (float*)d_out;
    float* ws  = (float*)d_ws;

    partial_kernel<<<kBlocks, 256, 0, stream>>>(
        pred_logits, pred_poly, tgt_poly, src_idx, labels, ws);
    finalize_kernel<<<1, 256, 0, stream>>>(ws, out);
}

// Round 3
// 73.829 us; speedup vs baseline: 1.1404x; 1.0590x over previous
//
#include <hip/hip_runtime.h>
#include <math.h>

// Problem constants: B=32, Q=256, M=128, P=64, C=20 (+1 no-object)
constexpr int kB = 32;
constexpr int kQ = 256;
constexpr int kM = 128;
constexpr int kP = 64;
constexpr int kC = 20;
constexpr int kC1 = kC + 1;

constexpr int kPairsPerBlock = 16;                       // 16 (b,m) pairs per 256-thread block
constexpr int kPolyBlocks   = (kB * kM) / kPairsPerBlock; // 256
constexpr int kCeBlocks     = kB;                         // 32
// ws layout (floats): poly partials [0,1024), dir partials [1024,2048), ce partials [2048,2176)
constexpr int kWsPoly = 0;
constexpr int kWsDir  = 1024;
constexpr int kWsCe   = 2048;

// ---------------------------------------------------------------------------
// Stage 1: fused partial sums, NO global atomics.  (Proven 73.1 µs topology:
// CE runs on its own 32 blocks, co-resident with poly blocks -> off the
// critical path.  Only change vs that baseline: float4 staging + float4
// chamfer inner loop, halving LDS/global instruction count in the hot loop.)
// ---------------------------------------------------------------------------
__global__ __launch_bounds__(256) void partial_kernel(const float* __restrict__ logits,
                                                      const float2* __restrict__ pred_poly,
                                                      const float2* __restrict__ tgt_poly,
                                                      const int* __restrict__ src_idx,
                                                      const int* __restrict__ labels,
                                                      float* __restrict__ ws) {
    const int tid  = threadIdx.x;
    const int lane = tid & 63;
    const int w    = tid >> 6;

    if (blockIdx.x < kPolyBlocks) {
        __shared__ float2 s_src[kPairsPerBlock][kP];
        __shared__ float2 s_tgt[kPairsPerBlock][kP];
        __shared__ int    s_sidx[kPairsPerBlock];

        const int base = blockIdx.x * kPairsPerBlock;  // global pair base
        const int b    = base >> 7;                    // kM = 128; block never spans b

        if (tid < kPairsPerBlock) s_sidx[tid] = src_idx[base + tid];
        __syncthreads();

        // Stage 16 pairs x (32 src + 32 tgt) float4 = 1024 float4 with 256 threads
        #pragma unroll
        for (int i = 0; i < 4; ++i) {
            const int g      = i * 256 + tid;
            const int p      = g >> 6;
            const int within = g & 63;
            if (within < 32) {
                const float4* s4 = reinterpret_cast<const float4*>(
                    pred_poly + (size_t)(b * kQ + s_sidx[p]) * kP);
                reinterpret_cast<float4*>(s_src[p])[within] = s4[within];
            } else {
                const float4* t4 = reinterpret_cast<const float4*>(
                    tgt_poly + (size_t)(base + p) * kP);
                reinterpret_cast<float4*>(s_tgt[p])[within - 32] = t4[within - 32];
            }
        }
        __syncthreads();

        float accPoly = 0.f, accDir = 0.f;
        #pragma unroll
        for (int i = 0; i < 4; ++i) {
            const int p = w * 4 + i;
            const float2 ms = s_src[p][lane];
            const float2 mt = s_tgt[p][lane];
            const float4* srow = reinterpret_cast<const float4*>(s_src[p]);
            const float4* trow = reinterpret_cast<const float4*>(s_tgt[p]);
            float minJ = 1e30f, minI = 1e30f;
            #pragma unroll 8
            for (int jj = 0; jj < kP / 2; ++jj) {      // 2 points per b128 read
                const float4 tj = trow[jj];            // broadcast — conflict-free
                const float4 sj = srow[jj];
                minJ = fminf(minJ, fminf(fabsf(ms.x - tj.x) + fabsf(ms.y - tj.y),
                                         fabsf(ms.x - tj.z) + fabsf(ms.y - tj.w)));
                minI = fminf(minI, fminf(fabsf(sj.x - mt.x) + fabsf(sj.y - mt.y),
                                         fabsf(sj.z - mt.x) + fabsf(sj.w - mt.y)));
            }
            float val = minI + minJ;
            #pragma unroll
            for (int off = 32; off > 0; off >>= 1) val += __shfl_down(val, off, 64);
            if (lane == 0) {
                accPoly += val;
                const float2 s0 = s_src[p][0], s1 = s_src[p][kP - 1];
                const float2 t0 = s_tgt[p][0], t1 = s_tgt[p][kP - 1];
                const float sdx = s1.x - s0.x, sdy = s1.y - s0.y;
                const float tdx = t1.x - t0.x, tdy = t1.y - t0.y;
                const float sn = sqrtf(sdx * sdx + sdy * sdy) + 1e-6f;
                const float tn = sqrtf(tdx * tdx + tdy * tdy) + 1e-6f;
                accDir += 1.0f - (sdx * tdx + sdy * tdy) / (sn * tn);
            }
        }
        if (lane == 0) {
            const int wid = blockIdx.x * 4 + w;  // 0..1023
            ws[kWsPoly + wid] = accPoly;
            ws[kWsDir + wid]  = accDir;
        }
    } else {
        // ---- cross entropy for batch b (separate blocks: off the critical path) ----
        const int b = blockIdx.x - kPolyBlocks;
        const int q = tid;
        __shared__ int c_idx[kM];
        __shared__ int c_lab[kM];
        if (tid < kM) {
            c_idx[tid] = src_idx[b * kM + tid];
            c_lab[tid] = labels[b * kM + tid];
        }
        __syncthreads();

        // numpy scatter: last occurrence wins -> ascending overwrite
        int tc = kC;
        #pragma unroll 4
        for (int m = 0; m < kM; ++m) {
            if (c_idx[m] == q) tc = c_lab[m];
        }

        const float* lp = logits + (size_t)(b * kQ + q) * kC1;
        float mx = -1e30f;
        #pragma unroll
        for (int c = 0; c < kC1; ++c) mx = fmaxf(mx, lp[c]);
        float se = 0.f, vt = 0.f;
        #pragma unroll
        for (int c = 0; c < kC1; ++c) {               // static index + cndmask select:
            const float x = lp[c];                     // no runtime-indexed array -> no scratch
            se += __expf(x - mx);
            if (c == tc) vt = x;
        }
        float val = -(vt - mx - __logf(se));

        #pragma unroll
        for (int off = 32; off > 0; off >>= 1) val += __shfl_down(val, off, 64);
        if (lane == 0) ws[kWsCe + b * 4 + w] = val;  // 128 partials
    }
}

// ---------------------------------------------------------------------------
// Stage 2: single block reduces 1024+1024+128 partials, writes out[0..2].
// ---------------------------------------------------------------------------
__global__ __launch_bounds__(256) void finalize_kernel(const float* __restrict__ ws,
                                                       float* __restrict__ out) {
    const int tid  = threadIdx.x;
    const int lane = tid & 63;
    const int w    = tid >> 6;

    float p = 0.f, d = 0.f, c = 0.f;
    #pragma unroll
    for (int k = 0; k < 4; ++k) {
        p += ws[kWsPoly + tid + 256 * k];
        d += ws[kWsDir + tid + 256 * k];
    }
    if (tid < 128) c = ws[kWsCe + tid];

    #pragma unroll
    for (int off = 32; off > 0; off >>= 1) {
        p += __shfl_down(p, off, 64);
        d += __shfl_down(d, off, 64);
        c += __shfl_down(c, off, 64);
    }

    __shared__ float sp[4], sd[4], sc[4];
    if (lane == 0) { sp[w] = p; sd[w] = d; sc[w] = c; }
    __syncthreads();
    if (tid == 0) {
        const float P = sp[0] + sp[1] + sp[2] + sp[3];
        const float D = sd[0] + sd[1] + sd[2] + sd[3];
        const float C = sc[0] + sc[1] + sc[2] + sc[3];
        out[0] = C * (1.0f / (float)(kB * kQ));
        out[1] = P * (0.5f / ((float)kP * (float)(kB * kM)));
        out[2] = D * (1.0f / (float)(kB * kM));
    }
}

extern "C" void kernel_launch(void* const* d_in, const int* in_sizes, int n_in,
                              void* d_out, int out_size, void* d_ws, size_t ws_size,
                              hipStream_t stream) {
    const float*  pred_logits = (const float*)d_in[0];
    const float2* pred_poly   = (const float2*)d_in[1];
    const float2* tgt_poly    = (const float2*)d_in[2];
    const int*    src_idx     = (const int*)d_in[3];
    const int*    labels     = (const int*)d_in[4];
    float* out = (float*)d_out;
    float* ws  = (float*)d_ws;

    partial_kernel<<<kPolyBlocks + kCeBlocks, 256, 0, stream>>>(
        pred_logits, pred_poly, tgt_poly, src_idx, labels, ws);
    finalize_kernel<<<1, 256, 0, stream>>>(ws, out);
}